// Round 1
// 247.756 us; speedup vs baseline: 1.0695x; 1.0695x over previous
//
#include <hip/hip_runtime.h>

// ---------------------------------------------------------------------------
// RGAT 2-hop, N=100000, E=1600000, D=64, R=64.
// R15 = R14 + (a) BKT_SHIFT 8->7 (782 buckets of 128 nodes, all binB blocks
// resident in one round); (b) binB stages the bucket CSR in LDS (128x65 ints,
// skewed) and writes out only ceil(deg/16)*16 entries per node as full 64B
// lines (kills fetch-on-write + cuts csr HBM writes ~2.5x); (c) binB emits a
// per-bucket degree-sorted perm (counting sort, 65 bins) so hop waves get
// 4 near-equal-degree nodes -> gated-tail waste ~25% -> ~8%; (d) hop adds an
// ungated 4-wide mid loop and consumes perm.
// Hop: 16-lane groups, 4 nodes/wave, lane=dim-quad; U,V bf16 ushort8 in
// LDS; DPP row_ror dot-reduce; v_dot2_f32_bf16 logits.
// ---------------------------------------------------------------------------

#define NEG_SLOPE 0.2f
#define CAP 64
#define BKT_SHIFT 7                  // 128 nodes per bucket
#define BKT_CAP 3072                 // stream slots per bucket (avg ~2046)

__device__ __forceinline__ float b2f_lo(unsigned x) {
    return __uint_as_float(x << 16);
}
__device__ __forceinline__ float b2f_hi(unsigned x) {
    return __uint_as_float(x & 0xffff0000u);
}
__device__ __forceinline__ unsigned short f2b(float x) {  // RNE
    unsigned u = __float_as_uint(x);
    unsigned r = u + 0x7fffu + ((u >> 16) & 1u);
    return (unsigned short)(r >> 16);
}

// D = a.bf16[0]*b.bf16[0] + a.bf16[1]*b.bf16[1] + c   (one VOP3P instr)
__device__ __forceinline__ float dot2bf(unsigned a, unsigned b, float c) {
    float d;
    asm("v_dot2_f32_bf16 %0, %1, %2, %3" : "=v"(d) : "v"(a), "v"(b), "v"(c));
    return d;
}

// sum over the 16 lanes of a row-group; result in ALL 16 lanes. VALU pipe.
__device__ __forceinline__ float ror_sum16(float x) {
#define ROR_ADD(ctrl)                                                          \
    x += __int_as_float(                                                       \
        __builtin_amdgcn_update_dpp(0, __float_as_int(x), ctrl, 0xf, 0xf, true))
    ROR_ADD(0x121);  // row_ror:1
    ROR_ADD(0x122);  // row_ror:2
    ROR_ADD(0x124);  // row_ror:4
    ROR_ADD(0x128);  // row_ror:8
#undef ROR_ADD
    return x;
}

// Fused init: blocks [0,R): Wuv projection; block R: zero bucket cursors;
// rest: cast ent -> bf16.
__global__ __launch_bounds__(256) void init_kernel(
    const float* __restrict__ W, const float* __restrict__ rel,
    unsigned short* __restrict__ Wuvb, const float* __restrict__ ent,
    unsigned short* __restrict__ entb, int* __restrict__ gcursor,
    int n4, int R, int nbkt) {
    if ((int)blockIdx.x < R) {
        int r = blockIdx.x;
        int i = threadIdx.x;  // use 128 of 256
        __shared__ float rels[64];
        if (i < 64) rels[i] = rel[r * 64 + i];
        __syncthreads();
        if (i < 128) {
            float s = 0.f;
#pragma unroll
            for (int j = 0; j < 64; ++j) s += W[i * 64 + j] * rels[j];
            int d = i & 63, half = i >> 6;
            Wuvb[r * 128 + (d >> 2) * 8 + half * 4 + (d & 3)] = f2b(s);
        }
    } else if ((int)blockIdx.x == R) {
        for (int i = threadIdx.x; i < nbkt; i += 256) gcursor[i] = 0;
    } else {
        int i = (blockIdx.x - R - 1) * 256 + threadIdx.x;
        if (i < n4) {
            float4 v = *(const float4*)(ent + (long)i * 4);
            ushort4 o = {f2b(v.x), f2b(v.y), f2b(v.z), f2b(v.w)};
            *(ushort4*)(entb + (long)i * 4) = o;
        }
    }
}

// ---------------- Phase A: partition edges into bucket streams ----------
__global__ __launch_bounds__(256) void binA_kernel(
    const int* __restrict__ head, const int* __restrict__ tail,
    const int* __restrict__ etype, int* __restrict__ gcursor,
    uint2* __restrict__ stream, int E, int nbkt) {
    __shared__ int lcnt[1024];
    __shared__ int lbase[1024];
    int nb = gridDim.x;
    long e0 = (long)blockIdx.x * E / nb;
    long e1 = (long)(blockIdx.x + 1) * E / nb;
    for (int i = threadIdx.x; i < nbkt; i += 256) lcnt[i] = 0;
    __syncthreads();
    for (long i = e0 + threadIdx.x; i < e1; i += 256)
        atomicAdd(&lcnt[head[i] >> BKT_SHIFT], 1);
    __syncthreads();
    for (int b = threadIdx.x; b < nbkt; b += 256) {
        lbase[b] = atomicAdd(gcursor + b, lcnt[b]);
        lcnt[b] = 0;
    }
    __syncthreads();
    for (long i = e0 + threadIdx.x; i < e1; i += 256) {
        int h = head[i];
        int b = h >> BKT_SHIFT;
        int entry = (tail[i] << 6) | etype[i];
        int p = lbase[b] + atomicAdd(&lcnt[b], 1);
        if (p < BKT_CAP)
            stream[(long)b * BKT_CAP + p] = make_uint2((unsigned)h, (unsigned)entry);
    }
}

// ---------------- Phase B: per-bucket LDS-staged CSR build --------------
// One block per 128-node bucket; CSR rows built in LDS then written out as
// full 64B lines (ceil(deg/16)*16 entries only). Also emits degree-sorted
// perm per bucket so hop waves see near-uniform degrees.
__global__ __launch_bounds__(256) void binB_kernel(
    const int* __restrict__ gcursor, const uint2* __restrict__ stream,
    int* __restrict__ deg, int* __restrict__ csr, int* __restrict__ perm,
    int N) {
    __shared__ int cnt[128];
    __shared__ int hist[CAP + 2];
    __shared__ unsigned csrS[128 * 65];  // 33.3 KB, skewed stride
    int b = blockIdx.x;
    if (threadIdx.x < 128) cnt[threadIdx.x] = 0;
    if (threadIdx.x < CAP + 2) hist[threadIdx.x] = 0;
    __syncthreads();
    int n = min(gcursor[b], BKT_CAP);
    const uint2* sp = stream + (long)b * BKT_CAP;
    for (int i = threadIdx.x; i < n; i += 256) {
        uint2 e = sp[i];
        int l = e.x & 127;
        int c = atomicAdd(&cnt[l], 1);
        if (c < CAP) csrS[l * 65 + c] = e.y;
    }
    __syncthreads();
    // deg write + degree-histogram rank
    int l = threadIdx.x, d = 0, rank = 0;
    bool v = false;
    if (l < 128) {
        int node = (b << BKT_SHIFT) + l;
        v = node < N;
        if (v) {
            deg[node] = cnt[l];
            d = min(cnt[l], CAP);
            rank = atomicAdd(&hist[d], 1);
        }
    }
    __syncthreads();
    if (threadIdx.x == 0) {  // exclusive prefix over 65 bins
        int s = 0;
        for (int i = 0; i <= CAP; ++i) { int t = hist[i]; hist[i] = s; s += t; }
    }
    __syncthreads();
    if (v) perm[(b << BKT_SHIFT) + hist[d] + rank] = (b << BKT_SHIFT) + l;
    // coalesced csr write-out: 16 groups of 16 lanes; groups within a wave
    // take nodes spaced 8 apart -> LDS bank windows overlap 2-way (free).
    int w4 = threadIdx.x >> 6, lane = threadIdx.x & 63;
    int q = lane >> 4, sL = lane & 15;
    for (int j = 0; j < 8; ++j) {
        int ln = ((j & 3) << 5) + (q << 3) + ((j >> 2) << 2) + w4;  // 0..127
        int node = (b << BKT_SHIFT) + ln;
        if (node < N) {
            int dcl = min(cnt[ln], CAP);
            for (int r = 0; r * 16 < dcl; ++r)
                csr[(long)node * CAP + r * 16 + sL] =
                    (int)csrS[ln * 65 + r * 16 + sL];
        }
    }
}

// ---------------- fused hop (16-lane groups) ----------------
// 512 threads = 8 waves = 32 nodes per block. Group = 16 lanes = 1 node,
// lane s owns dims 4s..4s+3. Nodes taken via degree-sorted perm.
__global__ __launch_bounds__(512) void hop_kernel(
    const int* __restrict__ degp, const int* __restrict__ csr,
    const int* __restrict__ perm,
    const unsigned short* __restrict__ Wuvb,
    const unsigned short* __restrict__ embb, const float* res_prev,
    unsigned short* embb_out, float* res_out, int N) {
    __shared__ unsigned short sUV[64 * 136];  // 17 KB, skewed stride
    for (int k = threadIdx.x; k < 64 * 128; k += 512) {
        int r = k >> 7, q = k & 127;
        sUV[r * 136 + q] = Wuvb[k];
    }
    __syncthreads();

    int tid = threadIdx.x;
    int s = tid & 15;
    int gi = blockIdx.x * 32 + (tid >> 4);
    bool valid = gi < N;
    int node = valid ? perm[gi] : 0;
    long nb64 = (long)node * 64;

    uint2 hdp = valid ? *(const uint2*)(embb + nb64 + s * 4)
                      : make_uint2(0u, 0u);

    int deg = valid ? min(degp[node], CAP) : 0;
    int r0 = node * CAP;
    // wave-uniform min/max degree over the wave's 4 groups (near-equal now)
    int dmin = min(min(__shfl(deg, 0), __shfl(deg, 16)),
                   min(__shfl(deg, 32), __shfl(deg, 48)));
    int dmax = max(max(__shfl(deg, 0), __shfl(deg, 16)),
                   max(__shfl(deg, 32), __shfl(deg, 48)));

    float a0 = 0.f, a1 = 0.f, a2 = 0.f, a3 = 0.f, l = 0.f;

    auto edge_body = [&](int pe, uint2 rw, bool gated, int idx) {
        int rr = pe & 63;
        uint4 uv = *(const uint4*)(sUV + rr * 136 + s * 8);
        float sd = dot2bf(hdp.x, uv.x, 0.f);   // hd01 . U01
        sd = dot2bf(hdp.y, uv.y, sd);          // hd23 . U23
        sd = dot2bf(rw.x, uv.z, sd);           // row01 . V01
        sd = dot2bf(rw.y, uv.w, sd);           // row23 . V23
        sd = ror_sum16(sd);                    // 64-dot in all 16 lanes
        float p = fmaxf(sd, NEG_SLOPE * sd);   // leaky (slope<1)
        float w = __expf(p);
        if (gated) w = (idx < deg) ? w : 0.f;
        l += w;
        float e0 = b2f_lo(rw.x), e1 = b2f_hi(rw.x);
        float e2 = b2f_lo(rw.y), e3 = b2f_hi(rw.y);
        a0 += w * e0; a1 += w * e1; a2 += w * e2; a3 += w * e3;
    };

    int c = 0;
    // fast path: 8 edges/iter, all groups full, no gating
    for (; c + 8 <= dmin; c += 8) {
        uint4 ea = *(const uint4*)(csr + r0 + c);
        uint4 eb = *(const uint4*)(csr + r0 + c + 4);
        int pe[8] = {(int)ea.x, (int)ea.y, (int)ea.z, (int)ea.w,
                     (int)eb.x, (int)eb.y, (int)eb.z, (int)eb.w};
        uint2 rw[8];
#pragma unroll
        for (int u = 0; u < 8; ++u)
            rw[u] = *(const uint2*)(embb + (long)(pe[u] >> 6) * 64 + s * 4);
#pragma unroll
        for (int u = 0; u < 8; ++u) edge_body(pe[u], rw[u], false, 0);
    }
    // ungated 4-wide mid loop
    for (; c + 4 <= dmin; c += 4) {
        uint4 e4 = *(const uint4*)(csr + r0 + c);
        int pe[4] = {(int)e4.x, (int)e4.y, (int)e4.z, (int)e4.w};
        uint2 rw[4];
#pragma unroll
        for (int u = 0; u < 4; ++u)
            rw[u] = *(const uint2*)(embb + (long)(pe[u] >> 6) * 64 + s * 4);
#pragma unroll
        for (int u = 0; u < 4; ++u) edge_body(pe[u], rw[u], false, 0);
    }
    // gated tail: 4 edges/iter; pe forced 0 before gather (poison safety)
    for (; c < dmax; c += 4) {
        uint4 e4 = *(const uint4*)(csr + r0 + c);
        int pe[4];
        pe[0] = (c + 0 < deg) ? (int)e4.x : 0;
        pe[1] = (c + 1 < deg) ? (int)e4.y : 0;
        pe[2] = (c + 2 < deg) ? (int)e4.z : 0;
        pe[3] = (c + 3 < deg) ? (int)e4.w : 0;
        uint2 rw[4];
#pragma unroll
        for (int u = 0; u < 4; ++u)
            rw[u] = *(const uint2*)(embb + (long)(pe[u] >> 6) * 64 + s * 4);
#pragma unroll
        for (int u = 0; u < 4; ++u) edge_body(pe[u], rw[u], true, c + u);
    }

    if (valid) {
        float hd0 = b2f_lo(hdp.x), hd1 = b2f_hi(hdp.x);
        float hd2 = b2f_lo(hdp.y), hd3 = b2f_hi(hdp.y);
        float inv = (l > 0.f) ? 1.f / l : 0.f;
        float v0 = hd0 + a0 * inv, v1 = hd1 + a1 * inv;
        float v2 = hd2 + a2 * inv, v3 = hd3 + a3 * inv;
        float sq = v0 * v0 + v1 * v1 + v2 * v2 + v3 * v3;
        sq = ror_sum16(sq);                       // group-uniform
        float rn = 1.f / fmaxf(sqrtf(sq), 1e-12f);
        v0 *= rn; v1 *= rn; v2 *= rn; v3 *= rn;
        if (embb_out) {
            ushort4 o = {f2b(v0), f2b(v1), f2b(v2), f2b(v3)};
            *(ushort4*)(embb_out + nb64 + s * 4) = o;
        }
        float4 rp = *(const float4*)(res_prev + nb64 + s * 4);
        float4 ro = {0.5f * rp.x + v0, 0.5f * rp.y + v1,
                     0.5f * rp.z + v2, 0.5f * rp.w + v3};
        *(float4*)(res_out + nb64 + s * 4) = ro;
    }
}

extern "C" void kernel_launch(void* const* d_in, const int* in_sizes, int n_in,
                              void* d_out, int out_size, void* d_ws, size_t ws_size,
                              hipStream_t stream) {
    const int*   edge_index = (const int*)d_in[0];   // [2, E]
    const int*   etype      = (const int*)d_in[1];   // [E]
    const float* ent        = (const float*)d_in[2]; // [N, 64]
    const float* rel        = (const float*)d_in[3]; // [R, 64]
    const float* W          = (const float*)d_in[4]; // [128, 64]

    const int E = in_sizes[1];
    const int N = in_sizes[2] / 64;
    const int R = in_sizes[3] / 64;
    const int* head = edge_index;
    const int* tail = edge_index + E;
    float* out = (float*)d_out;

    const int nbkt = ((N - 1) >> BKT_SHIFT) + 1;  // 782 for N=100000

    // workspace layout
    char* w = (char*)d_ws;
    unsigned short* Wuvb = (unsigned short*)w;  w += (size_t)R * 128 * 2;
    int* gcursor = (int*)w;                     w += 1024 * 4;
    int* deg = (int*)w;                         w += ((size_t)N + 64) * 4;
    int* csr = (int*)w;                         w += (size_t)N * CAP * 4;
    uint2* bstream = (uint2*)w;                 w += (size_t)nbkt * BKT_CAP * 8;
    unsigned short* entb = (unsigned short*)w;  w += (size_t)N * 64 * 2;
    unsigned short* emb1b = (unsigned short*)w; w += (size_t)N * 64 * 2;
    int* perm = (int*)w;                        w += ((size_t)N + 64) * 4;

    const int n4 = N * 16;                      // float4s to cast
    const int ib = R + 1 + (n4 + 255) / 256;
    const int hb = (N + 31) / 32;

    init_kernel<<<ib, 256, 0, stream>>>(W, rel, Wuvb, ent, entb, gcursor,
                                        n4, R, nbkt);

    // two-phase binned CSR build (graph constant across hops)
    binA_kernel<<<512, 256, 0, stream>>>(head, tail, etype, gcursor,
                                         bstream, E, nbkt);
    binB_kernel<<<nbkt, 256, 0, stream>>>(gcursor, bstream, deg, csr, perm, N);

    // hop 1
    hop_kernel<<<hb, 512, 0, stream>>>(deg, csr, perm, Wuvb, entb, ent,
                                       emb1b, out, N);
    // hop 2 (res in place)
    hop_kernel<<<hb, 512, 0, stream>>>(deg, csr, perm, Wuvb, emb1b, out,
                                       nullptr, out, N);
}

// Round 3
// 237.151 us; speedup vs baseline: 1.1174x; 1.0447x over previous
//
#include <hip/hip_runtime.h>

// ---------------------------------------------------------------------------
// RGAT 2-hop, N=100000, E=1600000, D=64, R=64.
// R16 (resubmit; previous bench died to container-acquire infra failure).
// R16 = R15 + binA rewrite: block-local counting sort by bucket in LDS
// (histogram -> 2-level scan -> LDS scatter with precomputed global dst),
// then COALESCED run-grouped stream write-out (~4x fewer scattered-store
// transactions); stream entry packed to ONE uint (l:7|tail:17|etype:6),
// halving stream write+read bytes. binB consumes packed uint stream.
// Hop unchanged: 16-lane groups, perm-sorted nodes, v_dot2_f32_bf16,
// DPP ror reduce, 8/4-wide ungated + gated tail.
// ---------------------------------------------------------------------------

#define NEG_SLOPE 0.2f
#define CAP 64
#define BKT_SHIFT 7                  // 128 nodes per bucket
#define BKT_CAP 3072                 // stream slots per bucket (avg ~2046)
#define EPB_MAX 3136                 // max edges per binA block (E/512=3125)

__device__ __forceinline__ float b2f_lo(unsigned x) {
    return __uint_as_float(x << 16);
}
__device__ __forceinline__ float b2f_hi(unsigned x) {
    return __uint_as_float(x & 0xffff0000u);
}
__device__ __forceinline__ unsigned short f2b(float x) {  // RNE
    unsigned u = __float_as_uint(x);
    unsigned r = u + 0x7fffu + ((u >> 16) & 1u);
    return (unsigned short)(r >> 16);
}

// D = a.bf16[0]*b.bf16[0] + a.bf16[1]*b.bf16[1] + c   (one VOP3P instr)
__device__ __forceinline__ float dot2bf(unsigned a, unsigned b, float c) {
    float d;
    asm("v_dot2_f32_bf16 %0, %1, %2, %3" : "=v"(d) : "v"(a), "v"(b), "v"(c));
    return d;
}

// sum over the 16 lanes of a row-group; result in ALL 16 lanes. VALU pipe.
__device__ __forceinline__ float ror_sum16(float x) {
#define ROR_ADD(ctrl)                                                          \
    x += __int_as_float(                                                       \
        __builtin_amdgcn_update_dpp(0, __float_as_int(x), ctrl, 0xf, 0xf, true))
    ROR_ADD(0x121);  // row_ror:1
    ROR_ADD(0x122);  // row_ror:2
    ROR_ADD(0x124);  // row_ror:4
    ROR_ADD(0x128);  // row_ror:8
#undef ROR_ADD
    return x;
}

// Fused init: blocks [0,R): Wuv projection; block R: zero bucket cursors;
// rest: cast ent -> bf16.
__global__ __launch_bounds__(256) void init_kernel(
    const float* __restrict__ W, const float* __restrict__ rel,
    unsigned short* __restrict__ Wuvb, const float* __restrict__ ent,
    unsigned short* __restrict__ entb, int* __restrict__ gcursor,
    int n4, int R, int nbkt) {
    if ((int)blockIdx.x < R) {
        int r = blockIdx.x;
        int i = threadIdx.x;  // use 128 of 256
        __shared__ float rels[64];
        if (i < 64) rels[i] = rel[r * 64 + i];
        __syncthreads();
        if (i < 128) {
            float s = 0.f;
#pragma unroll
            for (int j = 0; j < 64; ++j) s += W[i * 64 + j] * rels[j];
            int d = i & 63, half = i >> 6;
            Wuvb[r * 128 + (d >> 2) * 8 + half * 4 + (d & 3)] = f2b(s);
        }
    } else if ((int)blockIdx.x == R) {
        for (int i = threadIdx.x; i < nbkt; i += 256) gcursor[i] = 0;
    } else {
        int i = (blockIdx.x - R - 1) * 256 + threadIdx.x;
        if (i < n4) {
            float4 v = *(const float4*)(ent + (long)i * 4);
            ushort4 o = {f2b(v.x), f2b(v.y), f2b(v.z), f2b(v.w)};
            *(ushort4*)(entb + (long)i * 4) = o;
        }
    }
}

// ---------------- Phase A: counting-sort edges into bucket streams ------
// 512 threads. LDS counting sort of the block's edge chunk by bucket, then
// coalesced run-grouped write-out of packed uint entries.
__global__ __launch_bounds__(512) void binA_kernel(
    const int* __restrict__ head, const int* __restrict__ tail,
    const int* __restrict__ etype, int* __restrict__ gcursor,
    unsigned* __restrict__ stream, int E, int nbkt) {
    __shared__ int hist[1024];      // counts -> excl offsets -> cursors
    __shared__ int basev[1024];     // dst_linear = basev[b] + pos
    __shared__ int limv[1024];      // pos < limv[b]  =>  within BKT_CAP
    __shared__ int tsum[512];
    __shared__ uint2 sortedLDS[EPB_MAX];  // (entry, dst_linear)
    int t = threadIdx.x;
    int nb = gridDim.x;
    long e0 = (long)blockIdx.x * E / nb;
    long e1 = (long)(blockIdx.x + 1) * E / nb;
    int n = (int)(e1 - e0);
    for (int i = t; i < 1024; i += 512) hist[i] = 0;
    __syncthreads();
    for (int i = t; i < n; i += 512)
        atomicAdd(&hist[head[e0 + i] >> BKT_SHIFT], 1);
    __syncthreads();
    // 2-level exclusive scan over 1024 bins (2 bins/thread)
    int c0 = hist[2 * t], c1 = hist[2 * t + 1];
    int s = c0 + c1;
    tsum[t] = s;
    __syncthreads();
    for (int off = 1; off < 512; off <<= 1) {
        int v = (t >= off) ? tsum[t - off] : 0;
        __syncthreads();
        tsum[t] += v;
        __syncthreads();
    }
    int run = tsum[t] - s;  // exclusive prefix for bin 2t
    {
        int b0 = 2 * t, b1 = 2 * t + 1;
        int ex0 = run, ex1 = run + c0;
        int gb0 = 0, gb1 = 0;
        if (b0 < nbkt && c0 > 0) gb0 = atomicAdd(gcursor + b0, c0);
        if (b1 < nbkt && c1 > 0) gb1 = atomicAdd(gcursor + b1, c1);
        hist[b0] = ex0;
        hist[b1] = ex1;
        basev[b0] = b0 * BKT_CAP + gb0 - ex0;
        basev[b1] = b1 * BKT_CAP + gb1 - ex1;
        limv[b0] = ex0 + (BKT_CAP - gb0);
        limv[b1] = ex1 + (BKT_CAP - gb1);
    }
    __syncthreads();
    // scatter into LDS, sorted by bucket, with precomputed global dst
    for (int i = t; i < n; i += 512) {
        long idx = e0 + i;
        int h = head[idx];
        int b = h >> BKT_SHIFT;
        unsigned entry = ((unsigned)(h & ((1 << BKT_SHIFT) - 1)) << 23) |
                         ((unsigned)tail[idx] << 6) | (unsigned)etype[idx];
        int pos = atomicAdd(&hist[b], 1);
        unsigned dst = (pos < limv[b]) ? (unsigned)(basev[b] + pos)
                                       : 0xFFFFFFFFu;
        if (pos < EPB_MAX) sortedLDS[pos] = make_uint2(entry, dst);
    }
    __syncthreads();
    // coalesced write-out: consecutive i -> consecutive dst within runs
    int nn = n < EPB_MAX ? n : EPB_MAX;
    for (int i = t; i < nn; i += 512) {
        uint2 v = sortedLDS[i];
        if (v.y != 0xFFFFFFFFu) stream[v.y] = v.x;
    }
}

// ---------------- Phase B: per-bucket LDS-staged CSR build --------------
// One block per 128-node bucket; CSR rows built in LDS then written out as
// full 64B lines (ceil(deg/16)*16 entries only). Also emits degree-sorted
// perm per bucket so hop waves see near-uniform degrees.
__global__ __launch_bounds__(256) void binB_kernel(
    const int* __restrict__ gcursor, const unsigned* __restrict__ stream,
    int* __restrict__ deg, int* __restrict__ csr, int* __restrict__ perm,
    int N) {
    __shared__ int cnt[128];
    __shared__ int hist[CAP + 2];
    __shared__ unsigned csrS[128 * 65];  // 33.3 KB, skewed stride
    int b = blockIdx.x;
    if (threadIdx.x < 128) cnt[threadIdx.x] = 0;
    if (threadIdx.x < CAP + 2) hist[threadIdx.x] = 0;
    __syncthreads();
    int n = min(gcursor[b], BKT_CAP);
    const unsigned* sp = stream + (long)b * BKT_CAP;
    for (int i = threadIdx.x; i < n; i += 256) {
        unsigned e = sp[i];
        int l = (int)(e >> 23) & 127;
        int c = atomicAdd(&cnt[l], 1);
        if (c < CAP) csrS[l * 65 + c] = e & 0x7FFFFFu;
    }
    __syncthreads();
    // deg write + degree-histogram rank
    int l = threadIdx.x, d = 0, rank = 0;
    bool v = false;
    if (l < 128) {
        int node = (b << BKT_SHIFT) + l;
        v = node < N;
        if (v) {
            deg[node] = cnt[l];
            d = min(cnt[l], CAP);
            rank = atomicAdd(&hist[d], 1);
        }
    }
    __syncthreads();
    if (threadIdx.x == 0) {  // exclusive prefix over 65 bins
        int s = 0;
        for (int i = 0; i <= CAP; ++i) { int t = hist[i]; hist[i] = s; s += t; }
    }
    __syncthreads();
    if (v) perm[(b << BKT_SHIFT) + hist[d] + rank] = (b << BKT_SHIFT) + l;
    // coalesced csr write-out: 16 groups of 16 lanes; groups within a wave
    // take nodes spaced 8 apart -> LDS bank windows overlap 2-way (free).
    int w4 = threadIdx.x >> 6, lane = threadIdx.x & 63;
    int q = lane >> 4, sL = lane & 15;
    for (int j = 0; j < 8; ++j) {
        int ln = ((j & 3) << 5) + (q << 3) + ((j >> 2) << 2) + w4;  // 0..127
        int node = (b << BKT_SHIFT) + ln;
        if (node < N) {
            int dcl = min(cnt[ln], CAP);
            for (int r = 0; r * 16 < dcl; ++r)
                csr[(long)node * CAP + r * 16 + sL] =
                    (int)csrS[ln * 65 + r * 16 + sL];
        }
    }
}

// ---------------- fused hop (16-lane groups) ----------------
// 512 threads = 8 waves = 32 nodes per block. Group = 16 lanes = 1 node,
// lane s owns dims 4s..4s+3. Nodes taken via degree-sorted perm.
__global__ __launch_bounds__(512) void hop_kernel(
    const int* __restrict__ degp, const int* __restrict__ csr,
    const int* __restrict__ perm,
    const unsigned short* __restrict__ Wuvb,
    const unsigned short* __restrict__ embb, const float* res_prev,
    unsigned short* embb_out, float* res_out, int N) {
    __shared__ unsigned short sUV[64 * 136];  // 17 KB, skewed stride
    for (int k = threadIdx.x; k < 64 * 128; k += 512) {
        int r = k >> 7, q = k & 127;
        sUV[r * 136 + q] = Wuvb[k];
    }
    __syncthreads();

    int tid = threadIdx.x;
    int s = tid & 15;
    int gi = blockIdx.x * 32 + (tid >> 4);
    bool valid = gi < N;
    int node = valid ? perm[gi] : 0;
    long nb64 = (long)node * 64;

    uint2 hdp = valid ? *(const uint2*)(embb + nb64 + s * 4)
                      : make_uint2(0u, 0u);

    int deg = valid ? min(degp[node], CAP) : 0;
    int r0 = node * CAP;
    // wave-uniform min/max degree over the wave's 4 groups (near-equal now)
    int dmin = min(min(__shfl(deg, 0), __shfl(deg, 16)),
                   min(__shfl(deg, 32), __shfl(deg, 48)));
    int dmax = max(max(__shfl(deg, 0), __shfl(deg, 16)),
                   max(__shfl(deg, 32), __shfl(deg, 48)));

    float a0 = 0.f, a1 = 0.f, a2 = 0.f, a3 = 0.f, l = 0.f;

    auto edge_body = [&](int pe, uint2 rw, bool gated, int idx) {
        int rr = pe & 63;
        uint4 uv = *(const uint4*)(sUV + rr * 136 + s * 8);
        float sd = dot2bf(hdp.x, uv.x, 0.f);   // hd01 . U01
        sd = dot2bf(hdp.y, uv.y, sd);          // hd23 . U23
        sd = dot2bf(rw.x, uv.z, sd);           // row01 . V01
        sd = dot2bf(rw.y, uv.w, sd);           // row23 . V23
        sd = ror_sum16(sd);                    // 64-dot in all 16 lanes
        float p = fmaxf(sd, NEG_SLOPE * sd);   // leaky (slope<1)
        float w = __expf(p);
        if (gated) w = (idx < deg) ? w : 0.f;
        l += w;
        float e0 = b2f_lo(rw.x), e1 = b2f_hi(rw.x);
        float e2 = b2f_lo(rw.y), e3 = b2f_hi(rw.y);
        a0 += w * e0; a1 += w * e1; a2 += w * e2; a3 += w * e3;
    };

    int c = 0;
    // fast path: 8 edges/iter, all groups full, no gating
    for (; c + 8 <= dmin; c += 8) {
        uint4 ea = *(const uint4*)(csr + r0 + c);
        uint4 eb = *(const uint4*)(csr + r0 + c + 4);
        int pe[8] = {(int)ea.x, (int)ea.y, (int)ea.z, (int)ea.w,
                     (int)eb.x, (int)eb.y, (int)eb.z, (int)eb.w};
        uint2 rw[8];
#pragma unroll
        for (int u = 0; u < 8; ++u)
            rw[u] = *(const uint2*)(embb + (long)(pe[u] >> 6) * 64 + s * 4);
#pragma unroll
        for (int u = 0; u < 8; ++u) edge_body(pe[u], rw[u], false, 0);
    }
    // ungated 4-wide mid loop
    for (; c + 4 <= dmin; c += 4) {
        uint4 e4 = *(const uint4*)(csr + r0 + c);
        int pe[4] = {(int)e4.x, (int)e4.y, (int)e4.z, (int)e4.w};
        uint2 rw[4];
#pragma unroll
        for (int u = 0; u < 4; ++u)
            rw[u] = *(const uint2*)(embb + (long)(pe[u] >> 6) * 64 + s * 4);
#pragma unroll
        for (int u = 0; u < 4; ++u) edge_body(pe[u], rw[u], false, 0);
    }
    // gated tail: 4 edges/iter; pe forced 0 before gather (poison safety)
    for (; c < dmax; c += 4) {
        uint4 e4 = *(const uint4*)(csr + r0 + c);
        int pe[4];
        pe[0] = (c + 0 < deg) ? (int)e4.x : 0;
        pe[1] = (c + 1 < deg) ? (int)e4.y : 0;
        pe[2] = (c + 2 < deg) ? (int)e4.z : 0;
        pe[3] = (c + 3 < deg) ? (int)e4.w : 0;
        uint2 rw[4];
#pragma unroll
        for (int u = 0; u < 4; ++u)
            rw[u] = *(const uint2*)(embb + (long)(pe[u] >> 6) * 64 + s * 4);
#pragma unroll
        for (int u = 0; u < 4; ++u) edge_body(pe[u], rw[u], true, c + u);
    }

    if (valid) {
        float hd0 = b2f_lo(hdp.x), hd1 = b2f_hi(hdp.x);
        float hd2 = b2f_lo(hdp.y), hd3 = b2f_hi(hdp.y);
        float inv = (l > 0.f) ? 1.f / l : 0.f;
        float v0 = hd0 + a0 * inv, v1 = hd1 + a1 * inv;
        float v2 = hd2 + a2 * inv, v3 = hd3 + a3 * inv;
        float sq = v0 * v0 + v1 * v1 + v2 * v2 + v3 * v3;
        sq = ror_sum16(sq);                       // group-uniform
        float rn = 1.f / fmaxf(sqrtf(sq), 1e-12f);
        v0 *= rn; v1 *= rn; v2 *= rn; v3 *= rn;
        if (embb_out) {
            ushort4 o = {f2b(v0), f2b(v1), f2b(v2), f2b(v3)};
            *(ushort4*)(embb_out + nb64 + s * 4) = o;
        }
        float4 rp = *(const float4*)(res_prev + nb64 + s * 4);
        float4 ro = {0.5f * rp.x + v0, 0.5f * rp.y + v1,
                     0.5f * rp.z + v2, 0.5f * rp.w + v3};
        *(float4*)(res_out + nb64 + s * 4) = ro;
    }
}

extern "C" void kernel_launch(void* const* d_in, const int* in_sizes, int n_in,
                              void* d_out, int out_size, void* d_ws, size_t ws_size,
                              hipStream_t stream) {
    const int*   edge_index = (const int*)d_in[0];   // [2, E]
    const int*   etype      = (const int*)d_in[1];   // [E]
    const float* ent        = (const float*)d_in[2]; // [N, 64]
    const float* rel        = (const float*)d_in[3]; // [R, 64]
    const float* W          = (const float*)d_in[4]; // [128, 64]

    const int E = in_sizes[1];
    const int N = in_sizes[2] / 64;
    const int R = in_sizes[3] / 64;
    const int* head = edge_index;
    const int* tail = edge_index + E;
    float* out = (float*)d_out;

    const int nbkt = ((N - 1) >> BKT_SHIFT) + 1;  // 782 for N=100000

    // workspace layout
    char* w = (char*)d_ws;
    unsigned short* Wuvb = (unsigned short*)w;  w += (size_t)R * 128 * 2;
    int* gcursor = (int*)w;                     w += 1024 * 4;
    int* deg = (int*)w;                         w += ((size_t)N + 64) * 4;
    int* csr = (int*)w;                         w += (size_t)N * CAP * 4;
    unsigned* bstream = (unsigned*)w;           w += (size_t)nbkt * BKT_CAP * 4;
    unsigned short* entb = (unsigned short*)w;  w += (size_t)N * 64 * 2;
    unsigned short* emb1b = (unsigned short*)w; w += (size_t)N * 64 * 2;
    int* perm = (int*)w;                        w += ((size_t)N + 64) * 4;

    const int n4 = N * 16;                      // float4s to cast
    const int ib = R + 1 + (n4 + 255) / 256;
    const int hb = (N + 31) / 32;

    init_kernel<<<ib, 256, 0, stream>>>(W, rel, Wuvb, ent, entb, gcursor,
                                        n4, R, nbkt);

    // two-phase binned CSR build (graph constant across hops)
    binA_kernel<<<512, 512, 0, stream>>>(head, tail, etype, gcursor,
                                         bstream, E, nbkt);
    binB_kernel<<<nbkt, 256, 0, stream>>>(gcursor, bstream, deg, csr, perm, N);

    // hop 1
    hop_kernel<<<hb, 512, 0, stream>>>(deg, csr, perm, Wuvb, entb, ent,
                                       emb1b, out, N);
    // hop 2 (res in place)
    hop_kernel<<<hb, 512, 0, stream>>>(deg, csr, perm, Wuvb, emb1b, out,
                                       nullptr, out, N);
}